// Round 2
// baseline (247.360 us; speedup 1.0000x reference)
//
#include <hip/hip_runtime.h>

#define INF 3.4e38f

// v_med3_u32: middle of three uints (sorted-insert primitive)
__device__ __forceinline__ unsigned med3u(unsigned a, unsigned b, unsigned c) {
    unsigned d;
    asm("v_med3_u32 %0, %1, %2, %3" : "=v"(d) : "v"(a), "v"(b), "v"(c));
    return d;
}

// insert u into sorted top-5 key list (k0<=k1<=k2<=k3<=k4): 5 VALU ops
__device__ __forceinline__ void ins5(unsigned u, unsigned& k0, unsigned& k1,
                                     unsigned& k2, unsigned& k3, unsigned& k4)
{
    unsigned n1 = med3u(k0, k1, u);
    unsigned n2 = med3u(k1, k2, u);
    unsigned n3 = med3u(k2, k3, u);
    unsigned n4 = med3u(k3, k4, u);
    k0 = k0 < u ? k0 : u;
    k1 = n1; k2 = n2; k3 = n3; k4 = n4;
}

// exact (value,index) insert with index tiebreak (resolution only)
__device__ __forceinline__ void ins3t(float e, int ei,
                                      float& c0, float& c1, float& c2,
                                      int& i0, int& i1, int& i2)
{
    bool l0 = (e < c0) || (e == c0 && ei < i0);
    bool l1 = (e < c1) || (e == c1 && ei < i1);
    bool l2 = (e < c2) || (e == c2 && ei < i2);
    c2 = l1 ? c1 : (l2 ? e  : c2);
    i2 = l1 ? i1 : (l2 ? ei : i2);
    c1 = l0 ? c0 : (l1 ? e  : c1);
    i1 = l0 ? i0 : (l1 ? ei : i1);
    c0 = l0 ? e  : c0;
    i0 = l0 ? ei : i0;
}

// ---------------- Pack centroids: (x, y, z, 0.5*|c|^2) ----------------
__global__ __launch_bounds__(256) void fp_pack(
    const float* __restrict__ cents, float4* __restrict__ cpk, int M)
{
    int m = blockIdx.x * 256 + threadIdx.x;
    if (m < M) {
        float x = cents[3*m], y = cents[3*m+1], z = cents[3*m+2];
        cpk[m] = make_float4(x, y, z, 0.5f * fmaf(x, x, fmaf(y, y, z*z)));
    }
}

// ---------------- Kernel A: KNN + IDW interp + Linear1 -> hT ----------------
// Block = 256 thr / 64 vertices. Scan: lane = vertex, wave w scans centroid
// range [Mw/4, M(w+1)/4) — centroid operand is WAVE-UNIFORM -> compiler emits
// s_load (SMEM pipe), inner loop is pure VALU (no LDS staging, no ds_read).
// Packed key = (bits of 0.5*d^2+1e-4, low 11 bits = centroid index); top-5
// kept per wave, 4-way merged via tiny LDS buffer, exact d^2 re-resolution
// picks the true top-3 (guards quantization ties).
__global__ __launch_bounds__(256, 8) void fp_main(
    const float* __restrict__ verts,
    const float* __restrict__ cents,
    const float4* __restrict__ cpk,
    const float* __restrict__ feats,
    const float* __restrict__ W1,
    const float* __restrict__ b1,
    float* __restrict__ hT,
    int N, int M)
{
    // aliased region: merge buf uint[4][5][64] (5KB) / interpL [64][65] (16.64KB)
    __shared__ __align__(16) float smem[4160];
    __shared__ int   widx[64][3];
    __shared__ float wwt [64][3];
    float*    interpL = smem;
    unsigned* mk      = (unsigned*)smem;

    int t = threadIdx.x, lane = t & 63;
    int w  = __builtin_amdgcn_readfirstlane(t >> 6);
    int cw = w << 5;

    int v0 = blockIdx.x * 64;
    int vtx = v0 + lane;
    int vs  = vtx < N ? vtx : N - 1;
    float vx = verts[3*vs], vy = verts[3*vs+1], vz = verts[3*vs+2];

    // bias: s' = 0.5*|c|^2 - v.c + h = 0.5*d^2 + 1e-4  (>0, uint-order monotone)
    float h = 0.5f * fmaf(vx, vx, fmaf(vy, vy, vz*vz)) + 1e-4f;

    unsigned k0 = 0xFFFFFFFFu, k1 = 0xFFFFFFFFu, k2 = 0xFFFFFFFFu,
             k3 = 0xFFFFFFFFu, k4 = 0xFFFFFFFFu;

    int mw0 = (M * w) >> 2, mw1 = (M * (w + 1)) >> 2;
    #pragma unroll 8
    for (int m = mw0; m < mw1; ++m) {
        float4 c = cpk[m];                       // wave-uniform -> s_load
        float sp = fmaf(-vx, c.x, fmaf(-vy, c.y, fmaf(-vz, c.z, c.w + h)));
        unsigned u = (__float_as_uint(sp) & 0xFFFFF800u) | (unsigned)m;
        ins5(u, k0, k1, k2, k3, k4);
    }

    // publish per-wave top-5 (stride-1 across lanes: conflict-free)
    mk[(w*5 + 0)*64 + lane] = k0;
    mk[(w*5 + 1)*64 + lane] = k1;
    mk[(w*5 + 2)*64 + lane] = k2;
    mk[(w*5 + 3)*64 + lane] = k3;
    mk[(w*5 + 4)*64 + lane] = k4;
    __syncthreads();

    // 4-way merge: every wave folds in the other 3 waves' lists (keys are
    // globally unique via index bits -> order-independent; skip own list!)
    #pragma unroll
    for (int ww = 0; ww < 4; ++ww) {
        if (ww != w) {
            unsigned e0 = mk[(ww*5 + 0)*64 + lane];
            unsigned e1 = mk[(ww*5 + 1)*64 + lane];
            unsigned e2 = mk[(ww*5 + 2)*64 + lane];
            unsigned e3 = mk[(ww*5 + 3)*64 + lane];
            unsigned e4 = mk[(ww*5 + 4)*64 + lane];
            ins5(e0, k0, k1, k2, k3, k4);
            ins5(e1, k0, k1, k2, k3, k4);
            ins5(e2, k0, k1, k2, k3, k4);
            ins5(e3, k0, k1, k2, k3, k4);
            ins5(e4, k0, k1, k2, k3, k4);
        }
    }

    if (w == 0) {
        // exact d^2 for the 5 candidates from global cents (24KB, cache-hot),
        // exact top-3-of-5 with index tiebreak resolves quantization ties.
        int J0 = (int)(k0 & 2047u), J1 = (int)(k1 & 2047u), J2 = (int)(k2 & 2047u),
            J3 = (int)(k3 & 2047u), J4 = (int)(k4 & 2047u);
        float c0 = INF, c1 = INF, c2 = INF;
        int   i0 = 0x7fffffff, i1 = 0x7fffffff, i2 = 0x7fffffff;
        #pragma unroll
        for (int q = 0; q < 5; ++q) {
            int j = (q == 0) ? J0 : (q == 1) ? J1 : (q == 2) ? J2 : (q == 3) ? J3 : J4;
            float ax = cents[3*j], ay = cents[3*j+1], az = cents[3*j+2];
            float dx = vx - ax, dy = vy - ay, dz = vz - az;
            float dd = fmaf(dx, dx, fmaf(dy, dy, dz*dz));
            ins3t(dd, j, c0, c1, c2, i0, i1, i2);
        }
        float d0 = c0, d1 = c1, d2 = c2;
        bool z0 = (d0 == 0.0f), z1 = (d1 == 0.0f), z2 = (d2 == 0.0f);
        float w0, w1, w2;
        if (z0 || z1 || z2) {
            w0 = z0 ? 1.0f : 0.0f;
            w1 = z1 ? 1.0f : 0.0f;
            w2 = z2 ? 1.0f : 0.0f;
        } else {
            w0 = 1.0f / d0; w1 = 1.0f / d1; w2 = 1.0f / d2;
        }
        float winv = 1.0f / (w0 + w1 + w2);
        widx[lane][0] = i0; wwt[lane][0] = w0 * winv;
        widx[lane][1] = i1; wwt[lane][1] = w1 * winv;
        widx[lane][2] = i2; wwt[lane][2] = w2 * winv;
    }
    __syncthreads();   // mk reads done; widx/wwt published

    // gather: 4 threads/vertex, 16 feats each (overwrites merge-buf region)
    {
        int vloc = t >> 2, p = t & 3;
        int a0 = widx[vloc][0], a1 = widx[vloc][1], a2 = widx[vloc][2];
        float u0 = wwt[vloc][0], u1 = wwt[vloc][1], u2 = wwt[vloc][2];
        int fh = p * 16;
        const float4* f0 = (const float4*)(feats + (size_t)a0 * 64 + fh);
        const float4* f1 = (const float4*)(feats + (size_t)a1 * 64 + fh);
        const float4* f2 = (const float4*)(feats + (size_t)a2 * 64 + fh);
        float* dst = interpL + vloc * 65 + fh;
        #pragma unroll
        for (int q = 0; q < 4; ++q) {
            float4 A = f0[q], B = f1[q], C = f2[q];
            dst[4*q+0] = fmaf(u0, A.x, fmaf(u1, B.x, u2*C.x));
            dst[4*q+1] = fmaf(u0, A.y, fmaf(u1, B.y, u2*C.y));
            dst[4*q+2] = fmaf(u0, A.z, fmaf(u1, B.z, u2*C.z));
            dst[4*q+3] = fmaf(u0, A.w, fmaf(u1, B.w, u2*C.w));
        }
    }
    __syncthreads();

    // GEMM1: wave w -> cols [32w, 32w+32), lane -> vertex
    float acc[32];
    #pragma unroll
    for (int j = 0; j < 32; ++j) acc[j] = b1[cw + j];
    #pragma unroll 8
    for (int d = 0; d < 64; ++d) {
        float x = interpL[lane * 65 + d];
        const float* wr = W1 + d * 128 + cw;
        #pragma unroll
        for (int j = 0; j < 32; ++j) acc[j] = fmaf(x, wr[j], acc[j]);
    }
    int gv = v0 + lane;
    if (gv < N) {
        #pragma unroll
        for (int j = 0; j < 32; ++j)
            hT[(size_t)(cw + j) * N + gv] = acc[j];   // coalesced across lanes
    }
}

// ---------------- Reduce: BN stats straight from hT (L3-resident) ----------------
// 512 blocks: channel = bid & 127, segment = bid >> 7 (4 segs/channel).
__global__ __launch_bounds__(256) void fp_reduce(
    const float* __restrict__ hT,
    float* __restrict__ gstats, int N)
{
    __shared__ float red[8];
    int ch  = blockIdx.x & 127;
    int seg = blockIdx.x >> 7;
    const float* row = hT + (size_t)ch * N;
    float s = 0.0f, s2 = 0.0f;

    if ((N & 3) == 0) {
        int n4  = N >> 2;
        int len = (n4 + 3) >> 2;
        int a = seg * len, b = a + len; if (b > n4) b = n4;
        const float4* r4 = (const float4*)row;
        for (int i = a + threadIdx.x; i < b; i += 256) {
            float4 v = r4[i];
            s  += (v.x + v.y) + (v.z + v.w);
            s2 += fmaf(v.x, v.x, fmaf(v.y, v.y, fmaf(v.z, v.z, v.w * v.w)));
        }
    } else {
        int len = (N + 3) >> 2;
        int a = seg * len, b = a + len; if (b > N) b = N;
        for (int i = a + threadIdx.x; i < b; i += 256) {
            float v = row[i]; s += v; s2 = fmaf(v, v, s2);
        }
    }

    #pragma unroll
    for (int o = 32; o; o >>= 1) {
        s  += __shfl_xor(s, o);
        s2 += __shfl_xor(s2, o);
    }
    int w = threadIdx.x >> 6;
    if ((threadIdx.x & 63) == 0) { red[w] = s; red[4 + w] = s2; }
    __syncthreads();
    if (threadIdx.x == 0) {
        atomicAdd(&gstats[ch],       (red[0] + red[1]) + (red[2] + red[3]));
        atomicAdd(&gstats[128 + ch], (red[4] + red[5]) + (red[6] + red[7]));
    }
}

// ---------------- Kernel C: BN + ReLU + Linear2 ----------------
__global__ __launch_bounds__(256) void fp_bn_mlp2(
    const float* __restrict__ hT,
    const float* __restrict__ gstats,
    const float* __restrict__ gamma,
    const float* __restrict__ beta,
    const float* __restrict__ W2,
    const float* __restrict__ b2,
    float* __restrict__ out,
    int N)
{
    __shared__ float scS[128], shS[128];
    __shared__ __align__(16) float hl[128 * 68];   // phase2 reuse as [64][129]
    int t = threadIdx.x;
    if (t < 128) {
        float inv = 1.0f / (float)N;
        float mu  = gstats[t] * inv;
        float var = fmaf(-mu, mu, gstats[128 + t] * inv);
        var = fmaxf(var, 0.0f);
        float is = rsqrtf(var + 1e-5f);
        float sc = gamma[t] * is;
        scS[t] = sc;
        shS[t] = beta[t] - mu * sc;
    }
    __syncthreads();

    int r0 = blockIdx.x * 64;
    int N4 = N >> 2, r04 = r0 >> 2;
    const float4* hT4 = (const float4*)hT;

    // stage [128 ch][64 rows] with BN+ReLU applied, float4 loads
    #pragma unroll
    for (int jj = 0; jj < 8; ++jj) {
        int i4 = t + jj * 256;
        int k = i4 >> 4, r4 = i4 & 15;
        float4 v = make_float4(0.f, 0.f, 0.f, 0.f);
        if (r0 + 4*r4 < N) v = hT4[(size_t)k * N4 + r04 + r4];
        float sc = scS[k], sh = shS[k];
        float4 o;
        o.x = fmaxf(fmaf(v.x, sc, sh), 0.f);
        o.y = fmaxf(fmaf(v.y, sc, sh), 0.f);
        o.z = fmaxf(fmaf(v.z, sc, sh), 0.f);
        o.w = fmaxf(fmaf(v.w, sc, sh), 0.f);
        ((float4*)hl)[k * 17 + r4] = o;
    }
    __syncthreads();

    int lane = t & 63;
    int cw = __builtin_amdgcn_readfirstlane((t >> 6) << 5);
    float acc[32];
    #pragma unroll
    for (int j = 0; j < 32; ++j) acc[j] = b2[cw + j];
    #pragma unroll 4
    for (int k = 0; k < 128; ++k) {
        float x = hl[k * 68 + lane];
        const float* wr = W2 + k * 128 + cw;
        #pragma unroll
        for (int j = 0; j < 32; ++j) acc[j] = fmaf(x, wr[j], acc[j]);
    }
    __syncthreads();

    // transpose via LDS for coalesced float4 stores
    #pragma unroll
    for (int j = 0; j < 32; ++j) hl[lane * 129 + cw + j] = acc[j];
    __syncthreads();

    #pragma unroll
    for (int jj = 0; jj < 8; ++jj) {
        int i4 = t + jj * 256;
        int r = i4 >> 5, cq = (i4 & 31) << 2;
        int row = r0 + r;
        if (row < N) {
            float4 o4 = make_float4(hl[r*129 + cq],     hl[r*129 + cq + 1],
                                    hl[r*129 + cq + 2], hl[r*129 + cq + 3]);
            *(float4*)(out + (size_t)row * 128 + cq) = o4;
        }
    }
}

extern "C" void kernel_launch(void* const* d_in, const int* in_sizes, int n_in,
                              void* d_out, int out_size, void* d_ws, size_t ws_size,
                              hipStream_t stream)
{
    (void)n_in; (void)out_size; (void)ws_size;
    const float* verts = (const float*)d_in[0];
    const float* cents = (const float*)d_in[1];
    const float* feats = (const float*)d_in[2];
    const float* W1    = (const float*)d_in[3];
    const float* b1    = (const float*)d_in[4];
    const float* gamma = (const float*)d_in[5];
    const float* beta  = (const float*)d_in[6];
    const float* W2    = (const float*)d_in[7];
    const float* b2    = (const float*)d_in[8];
    float* out = (float*)d_out;

    int N = in_sizes[0] / 3;
    int M = in_sizes[1] / 3;

    float* gstats = (float*)d_ws;                       // 256 floats
    float* hT     = (float*)((char*)d_ws + 1024);       // [128, N]
    float4* cpk   = (float4*)(hT + (size_t)128 * N);    // [M] packed centroids

    hipMemsetAsync(gstats, 0, 256 * sizeof(float), stream);

    hipLaunchKernelGGL(fp_pack, dim3((M + 255) / 256), dim3(256), 0, stream,
                       cents, cpk, M);

    int nblk = (N + 63) / 64;
    hipLaunchKernelGGL(fp_main, dim3(nblk), dim3(256), 0, stream,
                       verts, cents, cpk, feats, W1, b1, hT, N, M);

    hipLaunchKernelGGL(fp_reduce, dim3(512), dim3(256), 0, stream,
                       hT, gstats, N);

    hipLaunchKernelGGL(fp_bn_mlp2, dim3(nblk), dim3(256), 0, stream,
                       hT, gstats, gamma, beta, W2, b2, out, N);
}

// Round 3
// 233.430 us; speedup vs baseline: 1.0597x; 1.0597x over previous
//
#include <hip/hip_runtime.h>

#define INF 3.4e38f

// v_med3_u32: middle of three uints (sorted-insert primitive)
__device__ __forceinline__ unsigned med3u(unsigned a, unsigned b, unsigned c) {
    unsigned d;
    asm("v_med3_u32 %0, %1, %2, %3" : "=v"(d) : "v"(a), "v"(b), "v"(c));
    return d;
}

// insert u into sorted top-5 key list (k0<=k1<=k2<=k3<=k4): 5 VALU ops
__device__ __forceinline__ void ins5(unsigned u, unsigned& k0, unsigned& k1,
                                     unsigned& k2, unsigned& k3, unsigned& k4)
{
    unsigned n1 = med3u(k0, k1, u);
    unsigned n2 = med3u(k1, k2, u);
    unsigned n3 = med3u(k2, k3, u);
    unsigned n4 = med3u(k3, k4, u);
    k0 = k0 < u ? k0 : u;
    k1 = n1; k2 = n2; k3 = n3; k4 = n4;
}

// exact (value,index) insert with index tiebreak (resolution only)
__device__ __forceinline__ void ins3t(float e, int ei,
                                      float& c0, float& c1, float& c2,
                                      int& i0, int& i1, int& i2)
{
    bool l0 = (e < c0) || (e == c0 && ei < i0);
    bool l1 = (e < c1) || (e == c1 && ei < i1);
    bool l2 = (e < c2) || (e == c2 && ei < i2);
    c2 = l1 ? c1 : (l2 ? e  : c2);
    i2 = l1 ? i1 : (l2 ? ei : i2);
    c1 = l0 ? c0 : (l1 ? e  : c1);
    i1 = l0 ? i0 : (l1 ? ei : i1);
    c0 = l0 ? e  : c0;
    i0 = l0 ? ei : i0;
}

// ---------------- Pack centroids: (x, y, z, 0.5*|c|^2) ----------------
__global__ __launch_bounds__(256) void fp_pack(
    const float* __restrict__ cents, float4* __restrict__ cpk, int M)
{
    int m = blockIdx.x * 256 + threadIdx.x;
    if (m < M) {
        float x = cents[3*m], y = cents[3*m+1], z = cents[3*m+2];
        cpk[m] = make_float4(x, y, z, 0.5f * fmaf(x, x, fmaf(y, y, z*z)));
    }
}

// ---------------- Kernel A: KNN + IDW interp + Linear1 -> hT ----------------
// Block = 512 thr / 8 waves / 64 vertices (lane = vertex). Wave w scans
// centroid range [Mw/8, M(w+1)/8) with wave-uniform cpk loads; packed key =
// (bits of 0.5*d^2+1e-4, low 11 bits = centroid index). Wave 0 merges the 8
// per-wave top-5 lists and exact-resolves top-3 (guards quantization ties).
// 18.6KB LDS + 512-thr blocks -> 4 blocks/CU = 32 waves/CU for latency hiding.
__global__ __launch_bounds__(512, 8) void fp_main(
    const float* __restrict__ verts,
    const float* __restrict__ cents,
    const float4* __restrict__ cpk,
    const float* __restrict__ feats,
    const float* __restrict__ W1,
    const float* __restrict__ b1,
    float* __restrict__ hT,
    int N, int M)
{
    // aliased region: merge buf uint[8][5][64] (10KB) / interpL [64][65] (16.64KB)
    __shared__ __align__(16) float smem[4160];
    __shared__ int   widx[64][3];
    __shared__ float wwt [64][3];
    float*    interpL = smem;
    unsigned* mk      = (unsigned*)smem;

    int t = threadIdx.x, lane = t & 63;
    int w  = __builtin_amdgcn_readfirstlane(t >> 6);   // 0..7
    int cw = w << 4;                                    // 16-col GEMM slice

    int v0 = blockIdx.x * 64;
    int vtx = v0 + lane;
    int vs  = vtx < N ? vtx : N - 1;
    float vx = verts[3*vs], vy = verts[3*vs+1], vz = verts[3*vs+2];

    // bias: s' = 0.5*|c|^2 - v.c + h = 0.5*d^2 + 1e-4  (>0, uint-order monotone)
    float h = 0.5f * fmaf(vx, vx, fmaf(vy, vy, vz*vz)) + 1e-4f;

    unsigned k0 = 0xFFFFFFFFu, k1 = 0xFFFFFFFFu, k2 = 0xFFFFFFFFu,
             k3 = 0xFFFFFFFFu, k4 = 0xFFFFFFFFu;

    int mw0 = (M * w) >> 3, mw1 = (M * (w + 1)) >> 3;
    #pragma unroll 8
    for (int m = mw0; m < mw1; ++m) {
        float4 c = cpk[m];                       // wave-uniform address
        float sp = fmaf(-vx, c.x, fmaf(-vy, c.y, fmaf(-vz, c.z, c.w + h)));
        unsigned u = (__float_as_uint(sp) & 0xFFFFF800u) | (unsigned)m;
        ins5(u, k0, k1, k2, k3, k4);
    }

    // publish per-wave top-5 (stride-1 across lanes: conflict-free)
    mk[(w*5 + 0)*64 + lane] = k0;
    mk[(w*5 + 1)*64 + lane] = k1;
    mk[(w*5 + 2)*64 + lane] = k2;
    mk[(w*5 + 3)*64 + lane] = k3;
    mk[(w*5 + 4)*64 + lane] = k4;
    __syncthreads();

    if (w == 0) {
        // fold in waves 1..7 (keys globally unique via index bits)
        #pragma unroll
        for (int ww = 1; ww < 8; ++ww) {
            unsigned e0 = mk[(ww*5 + 0)*64 + lane];
            unsigned e1 = mk[(ww*5 + 1)*64 + lane];
            unsigned e2 = mk[(ww*5 + 2)*64 + lane];
            unsigned e3 = mk[(ww*5 + 3)*64 + lane];
            unsigned e4 = mk[(ww*5 + 4)*64 + lane];
            ins5(e0, k0, k1, k2, k3, k4);
            ins5(e1, k0, k1, k2, k3, k4);
            ins5(e2, k0, k1, k2, k3, k4);
            ins5(e3, k0, k1, k2, k3, k4);
            ins5(e4, k0, k1, k2, k3, k4);
        }
        // exact d^2 for the 5 candidates from global cents (24KB, cache-hot),
        // exact top-3-of-5 with index tiebreak resolves quantization ties.
        int J0 = (int)(k0 & 2047u), J1 = (int)(k1 & 2047u), J2 = (int)(k2 & 2047u),
            J3 = (int)(k3 & 2047u), J4 = (int)(k4 & 2047u);
        float c0 = INF, c1 = INF, c2 = INF;
        int   i0 = 0x7fffffff, i1 = 0x7fffffff, i2 = 0x7fffffff;
        #pragma unroll
        for (int q = 0; q < 5; ++q) {
            int j = (q == 0) ? J0 : (q == 1) ? J1 : (q == 2) ? J2 : (q == 3) ? J3 : J4;
            float ax = cents[3*j], ay = cents[3*j+1], az = cents[3*j+2];
            float dx = vx - ax, dy = vy - ay, dz = vz - az;
            float dd = fmaf(dx, dx, fmaf(dy, dy, dz*dz));
            ins3t(dd, j, c0, c1, c2, i0, i1, i2);
        }
        float d0 = c0, d1 = c1, d2 = c2;
        bool z0 = (d0 == 0.0f), z1 = (d1 == 0.0f), z2 = (d2 == 0.0f);
        float w0, w1, w2;
        if (z0 || z1 || z2) {
            w0 = z0 ? 1.0f : 0.0f;
            w1 = z1 ? 1.0f : 0.0f;
            w2 = z2 ? 1.0f : 0.0f;
        } else {
            w0 = 1.0f / d0; w1 = 1.0f / d1; w2 = 1.0f / d2;
        }
        float winv = 1.0f / (w0 + w1 + w2);
        widx[lane][0] = i0; wwt[lane][0] = w0 * winv;
        widx[lane][1] = i1; wwt[lane][1] = w1 * winv;
        widx[lane][2] = i2; wwt[lane][2] = w2 * winv;
    }
    __syncthreads();   // mk reads done; widx/wwt published

    // gather: 8 threads/vertex, 8 feats each (overwrites merge-buf region)
    {
        int vloc = t >> 3, p = t & 7;
        int a0 = widx[vloc][0], a1 = widx[vloc][1], a2 = widx[vloc][2];
        float u0 = wwt[vloc][0], u1 = wwt[vloc][1], u2 = wwt[vloc][2];
        int fh = p * 8;
        const float4* f0 = (const float4*)(feats + (size_t)a0 * 64 + fh);
        const float4* f1 = (const float4*)(feats + (size_t)a1 * 64 + fh);
        const float4* f2 = (const float4*)(feats + (size_t)a2 * 64 + fh);
        float* dst = interpL + vloc * 65 + fh;
        #pragma unroll
        for (int q = 0; q < 2; ++q) {
            float4 A = f0[q], B = f1[q], C = f2[q];
            dst[4*q+0] = fmaf(u0, A.x, fmaf(u1, B.x, u2*C.x));
            dst[4*q+1] = fmaf(u0, A.y, fmaf(u1, B.y, u2*C.y));
            dst[4*q+2] = fmaf(u0, A.z, fmaf(u1, B.z, u2*C.z));
            dst[4*q+3] = fmaf(u0, A.w, fmaf(u1, B.w, u2*C.w));
        }
    }
    __syncthreads();

    // GEMM1: wave w -> cols [16w, 16w+16), lane -> vertex
    float acc[16];
    #pragma unroll
    for (int j = 0; j < 16; ++j) acc[j] = b1[cw + j];
    #pragma unroll 8
    for (int d = 0; d < 64; ++d) {
        float x = interpL[lane * 65 + d];
        const float* wr = W1 + d * 128 + cw;
        #pragma unroll
        for (int j = 0; j < 16; ++j) acc[j] = fmaf(x, wr[j], acc[j]);
    }
    int gv = v0 + lane;
    if (gv < N) {
        #pragma unroll
        for (int j = 0; j < 16; ++j)
            hT[(size_t)(cw + j) * N + gv] = acc[j];   // coalesced across lanes
    }
}

// ---------------- Reduce: BN stats straight from hT (L3-resident) ----------------
// 512 blocks: channel = bid & 127, segment = bid >> 7 (4 segs/channel).
__global__ __launch_bounds__(256) void fp_reduce(
    const float* __restrict__ hT,
    float* __restrict__ gstats, int N)
{
    __shared__ float red[8];
    int ch  = blockIdx.x & 127;
    int seg = blockIdx.x >> 7;
    const float* row = hT + (size_t)ch * N;
    float s = 0.0f, s2 = 0.0f;

    if ((N & 3) == 0) {
        int n4  = N >> 2;
        int len = (n4 + 3) >> 2;
        int a = seg * len, b = a + len; if (b > n4) b = n4;
        const float4* r4 = (const float4*)row;
        for (int i = a + threadIdx.x; i < b; i += 256) {
            float4 v = r4[i];
            s  += (v.x + v.y) + (v.z + v.w);
            s2 += fmaf(v.x, v.x, fmaf(v.y, v.y, fmaf(v.z, v.z, v.w * v.w)));
        }
    } else {
        int len = (N + 3) >> 2;
        int a = seg * len, b = a + len; if (b > N) b = N;
        for (int i = a + threadIdx.x; i < b; i += 256) {
            float v = row[i]; s += v; s2 = fmaf(v, v, s2);
        }
    }

    #pragma unroll
    for (int o = 32; o; o >>= 1) {
        s  += __shfl_xor(s, o);
        s2 += __shfl_xor(s2, o);
    }
    int w = threadIdx.x >> 6;
    if ((threadIdx.x & 63) == 0) { red[w] = s; red[4 + w] = s2; }
    __syncthreads();
    if (threadIdx.x == 0) {
        atomicAdd(&gstats[ch],       (red[0] + red[1]) + (red[2] + red[3]));
        atomicAdd(&gstats[128 + ch], (red[4] + red[5]) + (red[6] + red[7]));
    }
}

// ---------------- Kernel C: BN + ReLU + Linear2 (streaming, no input staging) ----------------
// 512 thr / 8 waves x 16 cols; x streamed from hT with BN+ReLU inline (L2/L3
// warm, coalesced); only the output-transpose buffer in LDS -> 4 blocks/CU.
__global__ __launch_bounds__(512, 8) void fp_bn_mlp2(
    const float* __restrict__ hT,
    const float* __restrict__ gstats,
    const float* __restrict__ gamma,
    const float* __restrict__ beta,
    const float* __restrict__ W2,
    const float* __restrict__ b2,
    float* __restrict__ out,
    int N)
{
    __shared__ float scS[128], shS[128];
    __shared__ __align__(16) float hl[64 * 129];   // output transpose buffer
    int t = threadIdx.x;
    if (t < 128) {
        float inv = 1.0f / (float)N;
        float mu  = gstats[t] * inv;
        float var = fmaf(-mu, mu, gstats[128 + t] * inv);
        var = fmaxf(var, 0.0f);
        float is = rsqrtf(var + 1e-5f);
        float sc = gamma[t] * is;
        scS[t] = sc;
        shS[t] = beta[t] - mu * sc;
    }
    __syncthreads();

    int lane = t & 63;
    int w  = __builtin_amdgcn_readfirstlane(t >> 6);
    int cw = w << 4;
    int r0 = blockIdx.x * 64;
    int gv = r0 + lane;
    int gs = gv < N ? gv : N - 1;

    float acc[16];
    #pragma unroll
    for (int j = 0; j < 16; ++j) acc[j] = b2[cw + j];

    const float* hp = hT + gs;
    #pragma unroll 4
    for (int k = 0; k < 128; ++k) {
        float x = hp[(size_t)k * N];                      // coalesced, L2/L3-warm
        x = fmaxf(fmaf(x, scS[k], shS[k]), 0.0f);         // BN + ReLU inline
        const float* wr = W2 + k * 128 + cw;
        #pragma unroll
        for (int j = 0; j < 16; ++j) acc[j] = fmaf(x, wr[j], acc[j]);
    }

    // transpose via LDS for coalesced float4 stores
    #pragma unroll
    for (int j = 0; j < 16; ++j) hl[lane * 129 + cw + j] = acc[j];
    __syncthreads();

    #pragma unroll
    for (int jj = 0; jj < 4; ++jj) {
        int i4 = t + jj * 512;
        int r = i4 >> 5, cq = (i4 & 31) << 2;
        int row = r0 + r;
        if (row < N) {
            float4 o4 = make_float4(hl[r*129 + cq],     hl[r*129 + cq + 1],
                                    hl[r*129 + cq + 2], hl[r*129 + cq + 3]);
            *(float4*)(out + (size_t)row * 128 + cq) = o4;
        }
    }
}

extern "C" void kernel_launch(void* const* d_in, const int* in_sizes, int n_in,
                              void* d_out, int out_size, void* d_ws, size_t ws_size,
                              hipStream_t stream)
{
    (void)n_in; (void)out_size; (void)ws_size;
    const float* verts = (const float*)d_in[0];
    const float* cents = (const float*)d_in[1];
    const float* feats = (const float*)d_in[2];
    const float* W1    = (const float*)d_in[3];
    const float* b1    = (const float*)d_in[4];
    const float* gamma = (const float*)d_in[5];
    const float* beta  = (const float*)d_in[6];
    const float* W2    = (const float*)d_in[7];
    const float* b2    = (const float*)d_in[8];
    float* out = (float*)d_out;

    int N = in_sizes[0] / 3;
    int M = in_sizes[1] / 3;

    float* gstats = (float*)d_ws;                       // 256 floats
    float* hT     = (float*)((char*)d_ws + 1024);       // [128, N]
    float4* cpk   = (float4*)(hT + (size_t)128 * N);    // [M] packed centroids

    hipMemsetAsync(gstats, 0, 256 * sizeof(float), stream);

    hipLaunchKernelGGL(fp_pack, dim3((M + 255) / 256), dim3(256), 0, stream,
                       cents, cpk, M);

    int nblk = (N + 63) / 64;
    hipLaunchKernelGGL(fp_main, dim3(nblk), dim3(512), 0, stream,
                       verts, cents, cpk, feats, W1, b1, hT, N, M);

    hipLaunchKernelGGL(fp_reduce, dim3(512), dim3(256), 0, stream,
                       hT, gstats, N);

    hipLaunchKernelGGL(fp_bn_mlp2, dim3(nblk), dim3(512), 0, stream,
                       hT, gstats, gamma, beta, W2, b2, out, N);
}

// Round 6
// 229.226 us; speedup vs baseline: 1.0791x; 1.0183x over previous
//
#include <hip/hip_runtime.h>

#define INF 3.4e38f

// v_med3_u32: middle of three uints (sorted-insert primitive)
__device__ __forceinline__ unsigned med3u(unsigned a, unsigned b, unsigned c) {
    unsigned d;
    asm("v_med3_u32 %0, %1, %2, %3" : "=v"(d) : "v"(a), "v"(b), "v"(c));
    return d;
}

// insert u into sorted top-5 key list (k0<=k1<=k2<=k3<=k4): 5 VALU ops
__device__ __forceinline__ void ins5(unsigned u, unsigned& k0, unsigned& k1,
                                     unsigned& k2, unsigned& k3, unsigned& k4)
{
    unsigned n1 = med3u(k0, k1, u);
    unsigned n2 = med3u(k1, k2, u);
    unsigned n3 = med3u(k2, k3, u);
    unsigned n4 = med3u(k3, k4, u);
    k0 = k0 < u ? k0 : u;
    k1 = n1; k2 = n2; k3 = n3; k4 = n4;
}

// exact (value,index) insert with index tiebreak (resolution only)
__device__ __forceinline__ void ins3t(float e, int ei,
                                      float& c0, float& c1, float& c2,
                                      int& i0, int& i1, int& i2)
{
    bool l0 = (e < c0) || (e == c0 && ei < i0);
    bool l1 = (e < c1) || (e == c1 && ei < i1);
    bool l2 = (e < c2) || (e == c2 && ei < i2);
    c2 = l1 ? c1 : (l2 ? e  : c2);
    i2 = l1 ? i1 : (l2 ? ei : i2);
    c1 = l0 ? c0 : (l1 ? e  : c1);
    i1 = l0 ? i0 : (l1 ? ei : i1);
    c0 = l0 ? e  : c0;
    i0 = l0 ? ei : i0;
}

// ---------------- Pack centroids: (x, y, z, 0.5*|c|^2) ----------------
__global__ __launch_bounds__(256) void fp_pack(
    const float* __restrict__ cents, float4* __restrict__ cpk, int M)
{
    int m = blockIdx.x * 256 + threadIdx.x;
    if (m < M) {
        float x = cents[3*m], y = cents[3*m+1], z = cents[3*m+2];
        cpk[m] = make_float4(x, y, z, 0.5f * fmaf(x, x, fmaf(y, y, z*z)));
    }
}

// ---------------- Kernel A: KNN + IDW interp + Linear1 -> hT ----------------
// Block = 512 thr / 8 waves / 64 vertices (lane = vertex). Wave w scans
// centroid range [Mw/8, M(w+1)/8) with wave-uniform cpk loads (SMEM); packed
// key = (bits of 0.5*d^2+1e-4, low 11 bits = centroid index). Wave 0 merges
// the 8 per-wave top-5 lists and exact-resolves top-3 (guards quantization
// ties).
__global__ __launch_bounds__(512, 8) void fp_main(
    const float* __restrict__ verts,
    const float* __restrict__ cents,
    const float4* __restrict__ cpk,
    const float* __restrict__ feats,
    const float* __restrict__ W1,
    const float* __restrict__ b1,
    float* __restrict__ hT,
    int N, int M)
{
    // aliased region: merge buf uint[8][5][64] (10KB) / interpL [64][65] (16.64KB)
    __shared__ __align__(16) float smem[4160];
    __shared__ int   widx[64][3];
    __shared__ float wwt [64][3];
    float*    interpL = smem;
    unsigned* mk      = (unsigned*)smem;

    int t = threadIdx.x, lane = t & 63;
    int w  = __builtin_amdgcn_readfirstlane(t >> 6);   // 0..7
    int cw = w << 4;                                    // 16-col GEMM slice

    int v0 = blockIdx.x * 64;
    int vtx = v0 + lane;
    int vs  = vtx < N ? vtx : N - 1;
    float vx = verts[3*vs], vy = verts[3*vs+1], vz = verts[3*vs+2];

    // bias: s' = 0.5*|c|^2 - v.c + h = 0.5*d^2 + 1e-4  (>0, uint-order monotone)
    float h = 0.5f * fmaf(vx, vx, fmaf(vy, vy, vz*vz)) + 1e-4f;

    unsigned k0 = 0xFFFFFFFFu, k1 = 0xFFFFFFFFu, k2 = 0xFFFFFFFFu,
             k3 = 0xFFFFFFFFu, k4 = 0xFFFFFFFFu;

    int mw0 = (M * w) >> 3, mw1 = (M * (w + 1)) >> 3;
    #pragma unroll 8
    for (int m = mw0; m < mw1; ++m) {
        float4 c = cpk[m];                       // wave-uniform address
        float sp = fmaf(-vx, c.x, fmaf(-vy, c.y, fmaf(-vz, c.z, c.w + h)));
        unsigned u = (__float_as_uint(sp) & 0xFFFFF800u) | (unsigned)m;
        ins5(u, k0, k1, k2, k3, k4);
    }

    // publish per-wave top-5 (stride-1 across lanes: conflict-free)
    mk[(w*5 + 0)*64 + lane] = k0;
    mk[(w*5 + 1)*64 + lane] = k1;
    mk[(w*5 + 2)*64 + lane] = k2;
    mk[(w*5 + 3)*64 + lane] = k3;
    mk[(w*5 + 4)*64 + lane] = k4;
    __syncthreads();

    if (w == 0) {
        // fold in waves 1..7 (keys globally unique via index bits)
        #pragma unroll
        for (int ww = 1; ww < 8; ++ww) {
            unsigned e0 = mk[(ww*5 + 0)*64 + lane];
            unsigned e1 = mk[(ww*5 + 1)*64 + lane];
            unsigned e2 = mk[(ww*5 + 2)*64 + lane];
            unsigned e3 = mk[(ww*5 + 3)*64 + lane];
            unsigned e4 = mk[(ww*5 + 4)*64 + lane];
            ins5(e0, k0, k1, k2, k3, k4);
            ins5(e1, k0, k1, k2, k3, k4);
            ins5(e2, k0, k1, k2, k3, k4);
            ins5(e3, k0, k1, k2, k3, k4);
            ins5(e4, k0, k1, k2, k3, k4);
        }
        // exact d^2 for the 5 candidates from global cents (24KB, cache-hot),
        // exact top-3-of-5 with index tiebreak resolves quantization ties.
        int J0 = (int)(k0 & 2047u), J1 = (int)(k1 & 2047u), J2 = (int)(k2 & 2047u),
            J3 = (int)(k3 & 2047u), J4 = (int)(k4 & 2047u);
        float c0 = INF, c1 = INF, c2 = INF;
        int   i0 = 0x7fffffff, i1 = 0x7fffffff, i2 = 0x7fffffff;
        #pragma unroll
        for (int q = 0; q < 5; ++q) {
            int j = (q == 0) ? J0 : (q == 1) ? J1 : (q == 2) ? J2 : (q == 3) ? J3 : J4;
            float ax = cents[3*j], ay = cents[3*j+1], az = cents[3*j+2];
            float dx = vx - ax, dy = vy - ay, dz = vz - az;
            float dd = fmaf(dx, dx, fmaf(dy, dy, dz*dz));
            ins3t(dd, j, c0, c1, c2, i0, i1, i2);
        }
        float d0 = c0, d1 = c1, d2 = c2;
        bool z0 = (d0 == 0.0f), z1 = (d1 == 0.0f), z2 = (d2 == 0.0f);
        float w0, w1, w2;
        if (z0 || z1 || z2) {
            w0 = z0 ? 1.0f : 0.0f;
            w1 = z1 ? 1.0f : 0.0f;
            w2 = z2 ? 1.0f : 0.0f;
        } else {
            w0 = 1.0f / d0; w1 = 1.0f / d1; w2 = 1.0f / d2;
        }
        float winv = 1.0f / (w0 + w1 + w2);
        widx[lane][0] = i0; wwt[lane][0] = w0 * winv;
        widx[lane][1] = i1; wwt[lane][1] = w1 * winv;
        widx[lane][2] = i2; wwt[lane][2] = w2 * winv;
    }
    __syncthreads();   // mk reads done; widx/wwt published

    // gather: 8 threads/vertex, 8 feats each (overwrites merge-buf region)
    {
        int vloc = t >> 3, p = t & 7;
        int a0 = widx[vloc][0], a1 = widx[vloc][1], a2 = widx[vloc][2];
        float u0 = wwt[vloc][0], u1 = wwt[vloc][1], u2 = wwt[vloc][2];
        int fh = p * 8;
        const float4* f0 = (const float4*)(feats + (size_t)a0 * 64 + fh);
        const float4* f1 = (const float4*)(feats + (size_t)a1 * 64 + fh);
        const float4* f2 = (const float4*)(feats + (size_t)a2 * 64 + fh);
        float* dst = interpL + vloc * 65 + fh;
        #pragma unroll
        for (int q = 0; q < 2; ++q) {
            float4 A = f0[q], B = f1[q], C = f2[q];
            dst[4*q+0] = fmaf(u0, A.x, fmaf(u1, B.x, u2*C.x));
            dst[4*q+1] = fmaf(u0, A.y, fmaf(u1, B.y, u2*C.y));
            dst[4*q+2] = fmaf(u0, A.z, fmaf(u1, B.z, u2*C.z));
            dst[4*q+3] = fmaf(u0, A.w, fmaf(u1, B.w, u2*C.w));
        }
    }
    __syncthreads();

    // GEMM1: wave w -> cols [16w, 16w+16), lane -> vertex
    float acc[16];
    #pragma unroll
    for (int j = 0; j < 16; ++j) acc[j] = b1[cw + j];
    #pragma unroll 8
    for (int d = 0; d < 64; ++d) {
        float x = interpL[lane * 65 + d];
        const float* wr = W1 + d * 128 + cw;
        #pragma unroll
        for (int j = 0; j < 16; ++j) acc[j] = fmaf(x, wr[j], acc[j]);
    }
    int gv = v0 + lane;
    if (gv < N) {
        #pragma unroll
        for (int j = 0; j < 16; ++j)
            hT[(size_t)(cw + j) * N + gv] = acc[j];   // coalesced across lanes
    }
}

// ---------------- Reduce: BN stats straight from hT (L3-resident) ----------------
// 512 blocks: channel = bid & 127, segment = bid >> 7 (4 segs/channel).
__global__ __launch_bounds__(256) void fp_reduce(
    const float* __restrict__ hT,
    float* __restrict__ gstats, int N)
{
    __shared__ float red[8];
    int ch  = blockIdx.x & 127;
    int seg = blockIdx.x >> 7;
    const float* row = hT + (size_t)ch * N;
    float s = 0.0f, s2 = 0.0f;

    if ((N & 3) == 0) {
        int n4  = N >> 2;
        int len = (n4 + 3) >> 2;
        int a = seg * len, b = a + len; if (b > n4) b = n4;
        const float4* r4 = (const float4*)row;
        for (int i = a + threadIdx.x; i < b; i += 256) {
            float4 v = r4[i];
            s  += (v.x + v.y) + (v.z + v.w);
            s2 += fmaf(v.x, v.x, fmaf(v.y, v.y, fmaf(v.z, v.z, v.w * v.w)));
        }
    } else {
        int len = (N + 3) >> 2;
        int a = seg * len, b = a + len; if (b > N) b = N;
        for (int i = a + threadIdx.x; i < b; i += 256) {
            float v = row[i]; s += v; s2 = fmaf(v, v, s2);
        }
    }

    #pragma unroll
    for (int o = 32; o; o >>= 1) {
        s  += __shfl_xor(s, o);
        s2 += __shfl_xor(s2, o);
    }
    int w = threadIdx.x >> 6;
    if ((threadIdx.x & 63) == 0) { red[w] = s; red[4 + w] = s2; }
    __syncthreads();
    if (threadIdx.x == 0) {
        atomicAdd(&gstats[ch],       (red[0] + red[1]) + (red[2] + red[3]));
        atomicAdd(&gstats[128 + ch], (red[4] + red[5]) + (red[6] + red[7]));
    }
}

// ---------------- Kernel C: BN + ReLU + Linear2 (LDS-staged, read-once) ----------------
// 512 thr / 8 waves x 16 cols. Block's hT slice [128 ch][64 rows] staged in
// LDS ONCE with BN+ReLU applied (each hT element read exactly once from
// global, float4 coalesced); GEMM reads LDS (lane-stride-1, conflict-free);
// same 34.8KB buffer reused for the output transpose. 4 blocks/CU.
__global__ __launch_bounds__(512, 8) void fp_bn_mlp2(
    const float* __restrict__ hT,
    const float* __restrict__ gstats,
    const float* __restrict__ gamma,
    const float* __restrict__ beta,
    const float* __restrict__ W2,
    const float* __restrict__ b2,
    float* __restrict__ out,
    int N)
{
    __shared__ float scS[128], shS[128];
    __shared__ __align__(16) float hl[128 * 68];   // stage [128][68]; reuse [64][129]
    int t = threadIdx.x;
    if (t < 128) {
        float inv = 1.0f / (float)N;
        float mu  = gstats[t] * inv;
        float var = fmaf(-mu, mu, gstats[128 + t] * inv);
        var = fmaxf(var, 0.0f);
        float is = rsqrtf(var + 1e-5f);
        float sc = gamma[t] * is;
        scS[t] = sc;
        shS[t] = beta[t] - mu * sc;
    }
    __syncthreads();

    int r0 = blockIdx.x * 64;
    int N4 = N >> 2, r04 = r0 >> 2;
    const float4* hT4 = (const float4*)hT;

    // stage [128 ch][64 rows] with BN+ReLU applied: 2048 float4 / 512 thr
    #pragma unroll
    for (int jj = 0; jj < 4; ++jj) {
        int i4 = t + jj * 512;
        int k = i4 >> 4, r4 = i4 & 15;
        float4 v = make_float4(0.f, 0.f, 0.f, 0.f);
        if (r0 + 4*r4 < N) v = hT4[(size_t)k * N4 + r04 + r4];
        float sc = scS[k], sh = shS[k];
        float4 o;
        o.x = fmaxf(fmaf(v.x, sc, sh), 0.f);
        o.y = fmaxf(fmaf(v.y, sc, sh), 0.f);
        o.z = fmaxf(fmaf(v.z, sc, sh), 0.f);
        o.w = fmaxf(fmaf(v.w, sc, sh), 0.f);
        ((float4*)hl)[k * 17 + r4] = o;
    }
    __syncthreads();

    int lane = t & 63;
    int w  = __builtin_amdgcn_readfirstlane(t >> 6);
    int cw = w << 4;

    float acc[16];
    #pragma unroll
    for (int j = 0; j < 16; ++j) acc[j] = b2[cw + j];
    #pragma unroll 8
    for (int k = 0; k < 128; ++k) {
        float x = hl[k * 68 + lane];               // stride-1 across lanes
        const float* wr = W2 + k * 128 + cw;       // scalar (SMEM) loads
        #pragma unroll
        for (int j = 0; j < 16; ++j) acc[j] = fmaf(x, wr[j], acc[j]);
    }
    __syncthreads();   // done reading staged hl

    // transpose via LDS (reuse hl as [64][129]) for coalesced float4 stores
    #pragma unroll
    for (int j = 0; j < 16; ++j) hl[lane * 129 + cw + j] = acc[j];
    __syncthreads();

    #pragma unroll
    for (int jj = 0; jj < 4; ++jj) {
        int i4 = t + jj * 512;
        int r = i4 >> 5, cq = (i4 & 31) << 2;
        int row = r0 + r;
        if (row < N) {
            float4 o4 = make_float4(hl[r*129 + cq],     hl[r*129 + cq + 1],
                                    hl[r*129 + cq + 2], hl[r*129 + cq + 3]);
            *(float4*)(out + (size_t)row * 128 + cq) = o4;
        }
    }
}

extern "C" void kernel_launch(void* const* d_in, const int* in_sizes, int n_in,
                              void* d_out, int out_size, void* d_ws, size_t ws_size,
                              hipStream_t stream)
{
    (void)n_in; (void)out_size; (void)ws_size;
    const float* verts = (const float*)d_in[0];
    const float* cents = (const float*)d_in[1];
    const float* feats = (const float*)d_in[2];
    const float* W1    = (const float*)d_in[3];
    const float* b1    = (const float*)d_in[4];
    const float* gamma = (const float*)d_in[5];
    const float* beta  = (const float*)d_in[6];
    const float* W2    = (const float*)d_in[7];
    const float* b2    = (const float*)d_in[8];
    float* out = (float*)d_out;

    int N = in_sizes[0] / 3;
    int M = in_sizes[1] / 3;

    float* gstats = (float*)d_ws;                       // 256 floats
    float* hT     = (float*)((char*)d_ws + 1024);       // [128, N]
    float4* cpk   = (float4*)(hT + (size_t)128 * N);    // [M] packed centroids

    hipMemsetAsync(gstats, 0, 256 * sizeof(float), stream);

    hipLaunchKernelGGL(fp_pack, dim3((M + 255) / 256), dim3(256), 0, stream,
                       cents, cpk, M);

    int nblk = (N + 63) / 64;
    hipLaunchKernelGGL(fp_main, dim3(nblk), dim3(512), 0, stream,
                       verts, cents, cpk, feats, W1, b1, hT, N, M);

    hipLaunchKernelGGL(fp_reduce, dim3(512), dim3(256), 0, stream,
                       hT, gstats, N);

    hipLaunchKernelGGL(fp_bn_mlp2, dim3(nblk), dim3(512), 0, stream,
                       hT, gstats, gamma, beta, W2, b2, out, N);
}